// Round 5
// baseline (2057.254 us; speedup 1.0000x reference)
//
#include <hip/hip_runtime.h>
#include <hip/hip_cooperative_groups.h>
#include <stdint.h>

namespace cg = cooperative_groups;
typedef unsigned long long u64;
typedef unsigned u32;

#define K 27
#define S 258
#define ENCMAX (4 * S * S * S)        // 68,694,048 possible keys

struct Params {
    const int* si; const float4* feat4;
    float* km; float* out_key; float* outF;
    u64* bits; u32* wprefix; int* tsums;
    int* minE; int* kid; int* flags; int* pos_of; u32* multib; int* bsums;
    int N, NK, NB, NT, NWp, nwords;
};

// inclusive block scan over 256 lanes; returns inclusive, total; s reusable after
__device__ __forceinline__ void block_scan256(int v, int* s, int* incl, int* tot) {
    int tid = threadIdx.x;
    s[tid] = v; __syncthreads();
    for (int off = 1; off < 256; off <<= 1) {
        int t = (tid >= off) ? s[tid - off] : 0;
        __syncthreads();
        s[tid] += t;
        __syncthreads();
    }
    *incl = s[tid];
    *tot = s[255];
    __syncthreads();
}

// single-block chunked exclusive scan of a[0..n); writes total to a[n]
__device__ void chunk_scan_excl(int* a, int n, int* s) {
    int tid = threadIdx.x;
    __shared__ int carry;
    if (tid == 0) carry = 0;
    __syncthreads();
    for (int base = 0; base < n; base += 256) {
        int i = base + tid;
        int v = (i < n) ? a[i] : 0;
        int incl, tot;
        block_scan256(v, s, &incl, &tot);
        if (i < n) a[i] = carry + incl - v;
        __syncthreads();
        if (tid == 0) carry += tot;
        __syncthreads();
    }
    if (tid == 0) a[n] = carry;
}

__global__ void __launch_bounds__(256, 4) fused(Params p) {
    cg::grid_group grid = cg::this_grid();
    __shared__ int s[256];
    int tid = threadIdx.x;
    int gtid = blockIdx.x * 256 + tid;
    int gstride = gridDim.x * 256;
    const int* si = p.si;
    int N = p.N, NK = p.NK;

    // ---- ph0: clear bits + multib ----
    for (int i = gtid; i < p.NWp; i += gstride) p.bits[i] = 0ull;
    for (int i = gtid; i < p.nwords; i += gstride) p.multib[i] = 0u;
    grid.sync();

    // ---- ph1: mark presence bits (one u64 atomicOr per z-run) ----
    for (int idx = gtid; idx < N * 9; idx += gstride) {
        int n = idx / 9, run = idx - n * 9;
        int ox = run / 3, oy = run - ox * 3;
        int b = si[n], x = si[N + n], y = si[2 * N + n], z = si[3 * N + n];
        unsigned enc0 = (unsigned)(((b * S + x + ox) * S + (y + oy)) * S + z);
        unsigned w = enc0 >> 6; int bit = enc0 & 63;
        atomicOr(&p.bits[w], 7ull << bit);
        if (bit > 61) atomicOr(&p.bits[w + 1], 7ull >> (64 - bit));
    }
    grid.sync();

    // ---- ph2a: per-4096-word tile popcounts ----
    for (int tile = blockIdx.x; tile < p.NT; tile += gridDim.x) {
        const u64* pw = p.bits + (size_t)tile * 4096;
        int sum = 0;
        for (int j = tid; j < 4096; j += 256) sum += __popcll(pw[j]);
        s[tid] = sum; __syncthreads();
        for (int off = 128; off > 0; off >>= 1) {
            if (tid < off) s[tid] += s[tid + off];
            __syncthreads();
        }
        if (tid == 0) p.tsums[tile] = s[0];
        __syncthreads();
    }
    grid.sync();

    // ---- ph2b: exclusive scan of tile sums (block 0) ----
    if (blockIdx.x == 0) chunk_scan_excl(p.tsums, p.NT, s);
    grid.sync();

    // ---- ph2c: per-word exclusive popcount prefix ----
    for (int tile = blockIdx.x; tile < p.NT; tile += gridDim.x) {
        size_t base = (size_t)tile * 4096 + (size_t)tid * 16;
        int pc[16]; int tsum = 0;
#pragma unroll
        for (int j = 0; j < 16; j++) { pc[j] = __popcll(p.bits[base + j]); tsum += pc[j]; }
        int incl, tot;
        block_scan256(tsum, s, &incl, &tot);
        int run = p.tsums[tile] + incl - tsum;
#pragma unroll
        for (int j = 0; j < 16; j++) { p.wprefix[base + j] = (u32)run; run += pc[j]; }
    }
    grid.sync();

    // ---- ph3: kid per entry + RACING plain store minE[kid]=e (any contributor) --
    for (int idx = gtid; idx < N * 9; idx += gstride) {
        int n = idx / 9, run = idx - n * 9;
        int ox = run / 3, oy = run - ox * 3;
        int b = si[n], x = si[N + n], y = si[2 * N + n], z = si[3 * N + n];
        unsigned enc0 = (unsigned)(((b * S + x + ox) * S + (y + oy)) * S + z);
        int e0 = n * K + run * 3;
#pragma unroll
        for (int oz = 0; oz < 3; ++oz) {
            unsigned enc = enc0 + oz;
            unsigned w = enc >> 6; int bit = enc & 63;
            int kd = (int)p.wprefix[w] + __popcll(p.bits[w] & ((1ull << bit) - 1));
            p.kid[e0 + oz] = kd;
            p.minE[kd] = e0 + oz;                 // race: arbitrary contributor wins
        }
    }
    grid.sync();

    // ---- ph4: fixup — only non-winners atomicMin (~NK-U ≈ 70k atomics) ----
    for (int e = gtid; e < NK; e += gstride) {
        int kd = p.kid[e];
        if (p.minE[kd] != e) atomicMin(&p.minE[kd], e);
    }
    grid.sync();

    // ---- ph5: flags, pos_of, multi-bitmap, per-tile flag sums ----
    for (int tile = blockIdx.x; tile < p.NB; tile += gridDim.x) {
        int base = tile * 4096 + tid * 16;
        int kv[16];
        *(int4*)(kv + 0)  = *(const int4*)(p.kid + base + 0);
        *(int4*)(kv + 4)  = *(const int4*)(p.kid + base + 4);
        *(int4*)(kv + 8)  = *(const int4*)(p.kid + base + 8);
        *(int4*)(kv + 12) = *(const int4*)(p.kid + base + 12);
        int f[16], pp[16]; int sum = 0;
#pragma unroll
        for (int j = 0; j < 16; j++) {
            int e = base + j;
            if (e < NK) {
                int pos = p.minE[kv[j]];
                pp[j] = pos;
                f[j] = (pos == e) ? 1 : 0;
                if (!f[j]) atomicOr(&p.multib[pos >> 5], 1u << (pos & 31));
            } else { pp[j] = 0; f[j] = 0; }
            sum += f[j];
        }
#pragma unroll
        for (int q = 0; q < 4; q++) {
            *(int4*)(p.flags + base + q * 4)  = *(int4*)(f + q * 4);
            *(int4*)(p.pos_of + base + q * 4) = *(int4*)(pp + q * 4);
        }
        s[tid] = sum; __syncthreads();
        for (int off = 128; off > 0; off >>= 1) {
            if (tid < off) s[tid] += s[tid + off];
            __syncthreads();
        }
        if (tid == 0) p.bsums[tile] = s[0];
        __syncthreads();
    }
    grid.sync();

    // ---- ph6: exclusive scan of bsums (block 0); total U -> bsums[NB] ----
    if (blockIdx.x == 0) chunk_scan_excl(p.bsums, p.NB, s);
    grid.sync();

    // ---- ph7: ranks at firsts + out_key rows (in-place flags -> ranks) ----
    for (int tile = blockIdx.x; tile < p.NB; tile += gridDim.x) {
        int base = tile * 4096 + tid * 16;
        int vals[16];
        *(int4*)(vals + 0)  = *(const int4*)(p.flags + base + 0);
        *(int4*)(vals + 4)  = *(const int4*)(p.flags + base + 4);
        *(int4*)(vals + 8)  = *(const int4*)(p.flags + base + 8);
        *(int4*)(vals + 12) = *(const int4*)(p.flags + base + 12);
        int tsum = 0;
#pragma unroll
        for (int j = 0; j < 16; j++) tsum += vals[j];
        int incl, tot;
        block_scan256(tsum, s, &incl, &tot);
        int offset = p.bsums[tile] + incl - tsum;
        int run = 0;
#pragma unroll
        for (int j = 0; j < 16; j++) {
            int e = base + j;
            int rank = offset + run;
            if (vals[j] && e < NK) {
                int n = e / K; int m = e - n * K;
                int x = si[N + n], y = si[2 * N + n], z = si[3 * N + n];
                int ox = m / 9; int rm = m - ox * 9; int oy = rm / 3; int oz = rm - oy * 3;
                p.out_key[(size_t)rank * 3 + 0] = (float)(x + ox - 1);
                p.out_key[(size_t)rank * 3 + 1] = (float)(y + oy - 1);
                p.out_key[(size_t)rank * 3 + 2] = (float)(z + oz - 1);
                p.flags[e] = rank;
            }
            run += vals[j];
        }
    }
    grid.sync();

    // ---- ph8: zero multi rows; tail rows >= U ----
    int U = p.bsums[p.NB];
    for (int i = gtid; i < p.nwords; i += gstride) {
        u32 bitsw = p.multib[i];
        while (bitsw) {
            int bit = __ffs(bitsw) - 1; bitsw &= bitsw - 1;
            int uid = p.flags[i * 32 + bit];
            float4 z = {0.f, 0.f, 0.f, 0.f};
            float4* q = (float4*)p.outF + (size_t)uid * 8;
#pragma unroll
            for (int j = 0; j < 8; j++) q[j] = z;
        }
    }
    int rows = NK - U;
    for (int i = gtid; i < rows; i += gstride) {
        int row = U + i;
        float4 z = {0.f, 0.f, 0.f, 0.f};
        float4* q = (float4*)p.outF + (size_t)row * 8;
#pragma unroll
        for (int j = 0; j < 8; j++) q[j] = z;
        p.out_key[(size_t)row * 3 + 0] = -1.0f;
        p.out_key[(size_t)row * 3 + 1] = -1.0f;
        p.out_key[(size_t)row * 3 + 2] = -1.0f;
    }
    grid.sync();

    // ---- ph9: fused kernel_map + coalesced scatter (8 lanes per row) ----
    int total = NK * 8;
    for (int idx = gtid; idx < total; idx += gstride) {
        int e = idx >> 3, g = idx & 7;
        int pos = p.pos_of[e];                    // 8 lanes same addr -> broadcast
        int uid = p.flags[pos];
        int multi = (p.multib[pos >> 5] >> (pos & 31)) & 1;
        int n = e / K, m = e - n * K;
        float4 v = p.feat4[(size_t)n * 8 + g];
        float* dst = p.outF + (size_t)uid * 32 + g * 4;
        if (multi) {
            atomicAdd(dst + 0, v.x);
            atomicAdd(dst + 1, v.y);
            atomicAdd(dst + 2, v.z);
            atomicAdd(dst + 3, v.w);
        } else {
            *(float4*)dst = v;                    // lanes g=0..7 -> 128B contiguous
        }
        if (g < 3)
            p.km[(size_t)e * 3 + g] = (g == 0) ? (float)n
                                   : ((g == 1) ? (float)uid : (float)m);
    }
}

extern "C" void kernel_launch(void* const* d_in, const int* in_sizes, int n_in,
                              void* d_out, int out_size, void* d_ws, size_t ws_size,
                              hipStream_t stream) {
    Params p;
    p.si = (const int*)d_in[0];
    p.feat4 = (const float4*)d_in[1];
    p.N = in_sizes[0] / 4;
    p.NK = p.N * K;                            // 2,700,000
    int NKp = (p.NK + 4095) & ~4095;
    p.NB = NKp / 4096;                         // ~660
    p.nwords = (p.NK + 31) / 32;

    int NW = (ENCMAX + 63) / 64;               // 1,073,345 bitmap words
    p.NT = (NW + 4095) / 4096;                 // 263 tiles
    p.NWp = p.NT * 4096;

    p.km = (float*)d_out;                      // [NK,3]
    p.out_key = p.km + (size_t)p.NK * 3;       // [NK,3]
    p.outF = p.km + (size_t)p.NK * 6;          // [NK,32]

    char* w = (char*)d_ws;
    p.bits    = (u64*)w; w += (size_t)p.NWp * 8;     // 8.6 MB
    p.wprefix = (u32*)w; w += (size_t)p.NWp * 4;     // 4.3 MB
    p.tsums   = (int*)w; w += (size_t)(p.NT + 1) * 4;
    p.minE    = (int*)w; w += (size_t)p.NK * 4;      // 10.8 MB (no init needed)
    p.kid     = (int*)w; w += (size_t)NKp * 4;
    p.flags   = (int*)w; w += (size_t)NKp * 4;       // becomes ranks
    p.pos_of  = (int*)w; w += (size_t)NKp * 4;
    p.multib  = (u32*)w; w += (size_t)p.nwords * 4;
    p.bsums   = (int*)w;

    void* args[] = { &p };
    hipLaunchCooperativeKernel((const void*)fused, dim3(1024), dim3(256),
                               args, 0, stream);
}

// Round 6
// 740.965 us; speedup vs baseline: 2.7765x; 2.7765x over previous
//
#include <hip/hip_runtime.h>
#include <stdint.h>

typedef unsigned long long u64;
typedef unsigned u32;

#define K 27
#define S 258
#define ENCMAX (4 * S * S * S)        // 68,694,048 possible keys

// ---------- pass 1: mark presence bits (one u64 atomicOr per z-run) ----------
__global__ void k_mark(const int* __restrict__ si, int N, u64* __restrict__ bits) {
    int idx = blockIdx.x * blockDim.x + threadIdx.x;
    if (idx >= N * 9) return;
    int n = idx / 9, run = idx - n * 9;
    int ox = run / 3, oy = run - ox * 3;
    int b = si[n], x = si[N + n], y = si[2 * N + n], z = si[3 * N + n];
    unsigned enc0 = (unsigned)(((b * S + x + ox) * S + (y + oy)) * S + z);
    unsigned w = enc0 >> 6; int bit = enc0 & 63;
    atomicOr(&bits[w], 7ull << bit);
    if (bit > 61) atomicOr(&bits[w + 1], 7ull >> (64 - bit));
}

// ---------- s1: per-4096-word tile popcount sums ----------
__global__ void s1_tilesum(const u64* __restrict__ bits, int* __restrict__ tsums) {
    __shared__ int s[256];
    int tid = threadIdx.x;
    const u64* p = bits + (size_t)blockIdx.x * 4096;
    int sum = 0;
    for (int j = tid; j < 4096; j += 256) sum += __popcll(p[j]);
    s[tid] = sum; __syncthreads();
    for (int off = 128; off > 0; off >>= 1) {
        if (tid < off) s[tid] += s[tid + off];
        __syncthreads();
    }
    if (tid == 0) tsums[blockIdx.x] = s[0];
}

// ---------- single-block exclusive scan (n <= 1024); total -> a[n] ----------
__global__ void k_scanB(int* __restrict__ a, int n) {
    __shared__ int s[1024];
    int tid = threadIdx.x;
    int v = (tid < n) ? a[tid] : 0;
    s[tid] = v; __syncthreads();
    for (int off = 1; off < 1024; off <<= 1) {
        int t = (tid >= off) ? s[tid - off] : 0;
        __syncthreads();
        s[tid] += t;
        __syncthreads();
    }
    if (tid == 1023) a[n] = s[1023];
    if (tid < n) a[tid] = s[tid] - v;
}

// ---------- s3: per-word exclusive popcount prefix ----------
__global__ void s3_wprefix(const u64* __restrict__ bits, const int* __restrict__ tsums,
                           u32* __restrict__ wprefix) {
    __shared__ int s[256];
    int tid = threadIdx.x;
    size_t base = (size_t)blockIdx.x * 4096 + (size_t)tid * 16;
    int pc[16]; int tsum = 0;
#pragma unroll
    for (int j = 0; j < 16; j++) { pc[j] = __popcll(bits[base + j]); tsum += pc[j]; }
    s[tid] = tsum; __syncthreads();
    for (int off = 1; off < 256; off <<= 1) {
        int t = (tid >= off) ? s[tid - off] : 0;
        __syncthreads();
        s[tid] += t;
        __syncthreads();
    }
    int run = tsums[blockIdx.x] + s[tid] - tsum;
#pragma unroll
    for (int j = 0; j < 16; j++) { wprefix[base + j] = (u32)run; run += pc[j]; }
}

// ---------- pass 2: dense key id per entry + min-e per key (L2-hot atomics) ---
__global__ void k_kid(const int* __restrict__ si, int N,
                      const u64* __restrict__ bits, const u32* __restrict__ wprefix,
                      int* __restrict__ kid, int* __restrict__ minE) {
    int idx = blockIdx.x * blockDim.x + threadIdx.x;
    if (idx >= N * 9) return;
    int n = idx / 9, run = idx - n * 9;
    int ox = run / 3, oy = run - ox * 3;
    int b = si[n], x = si[N + n], y = si[2 * N + n], z = si[3 * N + n];
    unsigned enc0 = (unsigned)(((b * S + x + ox) * S + (y + oy)) * S + z);
    int e0 = n * K + run * 3;
#pragma unroll
    for (int oz = 0; oz < 3; ++oz) {
        unsigned enc = enc0 + oz;
        unsigned w = enc >> 6; int bit = enc & 63;
        int kd = (int)wprefix[w] + __popcll(bits[w] & ((1ull << bit) - 1));
        kid[e0 + oz] = kd;
        atomicMin(&minE[kd], e0 + oz);            // fire-and-forget, cache-hot
    }
}

// ---------- pass 3: per-tile first-count + multi-bitmap (keyed by kd) --------
__global__ void k_flagsum(const int* __restrict__ kid, const int* __restrict__ minE,
                          int NK, u32* __restrict__ multibk, int* __restrict__ bsums) {
    __shared__ int s[256];
    int tid = threadIdx.x;
    int base = blockIdx.x * 4096 + tid * 16;
    int kv[16];
    *(int4*)(kv + 0)  = *(const int4*)(kid + base + 0);
    *(int4*)(kv + 4)  = *(const int4*)(kid + base + 4);
    *(int4*)(kv + 8)  = *(const int4*)(kid + base + 8);
    *(int4*)(kv + 12) = *(const int4*)(kid + base + 12);
    int sum = 0;
#pragma unroll
    for (int j = 0; j < 16; j++) {
        int e = base + j;
        if (e < NK) {
            int kd = kv[j];
            if (minE[kd] == e) sum += 1;
            else atomicOr(&multibk[kd >> 5], 1u << (kd & 31));   // loser marks key
        }
    }
    s[tid] = sum; __syncthreads();
    for (int off = 128; off > 0; off >>= 1) {
        if (tid < off) s[tid] += s[tid + off];
        __syncthreads();
    }
    if (tid == 0) bsums[blockIdx.x] = s[0];
}

// ---------- scan C: ranks at firsts -> rank_key[kd], out_key rows ------------
__global__ void k_scanC(const int* __restrict__ kid, const int* __restrict__ minE,
                        const int* __restrict__ bsums, const int* __restrict__ si,
                        int N, int NK, float* __restrict__ out_key,
                        int* __restrict__ rank_key) {
    __shared__ int s[256];
    int tid = threadIdx.x;
    int base = blockIdx.x * 4096 + tid * 16;
    int kv[16];
    *(int4*)(kv + 0)  = *(const int4*)(kid + base + 0);
    *(int4*)(kv + 4)  = *(const int4*)(kid + base + 4);
    *(int4*)(kv + 8)  = *(const int4*)(kid + base + 8);
    *(int4*)(kv + 12) = *(const int4*)(kid + base + 12);
    int f[16]; int tsum = 0;
#pragma unroll
    for (int j = 0; j < 16; j++) {
        int e = base + j;
        f[j] = (e < NK && minE[kv[j]] == e) ? 1 : 0;
        tsum += f[j];
    }
    s[tid] = tsum; __syncthreads();
    for (int off = 1; off < 256; off <<= 1) {
        int t = (tid >= off) ? s[tid - off] : 0;
        __syncthreads();
        s[tid] += t;
        __syncthreads();
    }
    int offset = bsums[blockIdx.x] + s[tid] - tsum;
    int run = 0;
#pragma unroll
    for (int j = 0; j < 16; j++) {
        int e = base + j;
        if (f[j]) {
            int rank = offset + run;
            int n = e / K; int m = e - n * K;
            int x = si[N + n], y = si[2 * N + n], z = si[3 * N + n];
            int ox = m / 9; int rm = m - ox * 9; int oy = rm / 3; int oz = rm - oy * 3;
            out_key[(size_t)rank * 3 + 0] = (float)(x + ox - 1);
            out_key[(size_t)rank * 3 + 1] = (float)(y + oy - 1);
            out_key[(size_t)rank * 3 + 2] = (float)(z + oz - 1);
            rank_key[kv[j]] = rank;
        }
        run += f[j];
    }
}

// ---------- zero multi rows + tail rows, out_key tail ----------
__global__ void k_zmt(const u32* __restrict__ multibk, const int* __restrict__ rank_key,
                      const int* __restrict__ bsums, int NB, int NK, int nkw,
                      float* __restrict__ out_key, float4* __restrict__ outF4) {
    int U = bsums[NB];
    int i0 = blockIdx.x * blockDim.x + threadIdx.x;
    int gs = gridDim.x * blockDim.x;
    float4 z = {0.f, 0.f, 0.f, 0.f};
    for (int i = i0; i < nkw; i += gs) {
        u32 b = multibk[i];
        while (b) {
            int bit = __ffs(b) - 1; b &= b - 1;
            int uid = rank_key[i * 32 + bit];
            float4* q = outF4 + (size_t)uid * 8;
#pragma unroll
            for (int j = 0; j < 8; j++) q[j] = z;
        }
    }
    int rows = NK - U;
    for (int i = i0; i < rows; i += gs) {
        int row = U + i;
        float4* q = outF4 + (size_t)row * 8;
#pragma unroll
        for (int j = 0; j < 8; j++) q[j] = z;
        out_key[(size_t)row * 3 + 0] = -1.0f;
        out_key[(size_t)row * 3 + 1] = -1.0f;
        out_key[(size_t)row * 3 + 2] = -1.0f;
    }
}

// ---------- final: kernel_map + coalesced feature scatter (8 lanes/row) ------
__global__ void k_final(const int* __restrict__ kid, const int* __restrict__ rank_key,
                        const u32* __restrict__ multibk,
                        const float4* __restrict__ feat4,
                        float* __restrict__ km, float* __restrict__ outF, int NK) {
    int idx = blockIdx.x * blockDim.x + threadIdx.x;
    if (idx >= NK * 8) return;
    int e = idx >> 3, g = idx & 7;
    int kd = kid[e];                              // 8 lanes same addr -> broadcast
    int uid = rank_key[kd];                       // one hot gather
    int multi = (multibk[kd >> 5] >> (kd & 31)) & 1;
    int n = e / K, m = e - n * K;
    float4 v = feat4[(size_t)n * 8 + g];          // wave covers 8 consecutive e
    float* dst = outF + (size_t)uid * 32 + g * 4;
    if (multi) {
        atomicAdd(dst + 0, v.x);
        atomicAdd(dst + 1, v.y);
        atomicAdd(dst + 2, v.z);
        atomicAdd(dst + 3, v.w);
    } else {
        *(float4*)dst = v;                        // uid near-monotone -> seq lines
    }
    if (g < 3)
        km[(size_t)e * 3 + g] = (g == 0) ? (float)n
                               : ((g == 1) ? (float)uid : (float)m);
}

extern "C" void kernel_launch(void* const* d_in, const int* in_sizes, int n_in,
                              void* d_out, int out_size, void* d_ws, size_t ws_size,
                              hipStream_t stream) {
    const int* si = (const int*)d_in[0];
    const float4* feat4 = (const float4*)d_in[1];
    int N = in_sizes[0] / 4;
    int NK = N * K;                            // 2,700,000
    int NKp = (NK + 4095) & ~4095;
    int NB = NKp / 4096;                       // ~660 (<=1024)
    int nkw = (NK + 31) / 32;

    int NW = (ENCMAX + 63) / 64;               // 1,073,345 bitmap words
    int NT = (NW + 4095) / 4096;               // 263 tiles (<=1024)
    int NWp = NT * 4096;

    float* km = (float*)d_out;                 // [NK,3]
    float* out_key = km + (size_t)NK * 3;      // [NK,3]
    float* outF = km + (size_t)NK * 6;         // [NK,32]

    char* w = (char*)d_ws;
    u64* bits     = (u64*)w; w += (size_t)NWp * 8;      // 8.6 MB
    u32* wprefix  = (u32*)w; w += (size_t)NWp * 4;      // 4.3 MB
    int* tsums    = (int*)w; w += (size_t)(NT + 1) * 4;
    int* minE     = (int*)w; w += (size_t)NK * 4;       // 10.8 MB
    int* kid      = (int*)w; w += (size_t)NKp * 4;      // 10.8 MB
    int* rank_key = (int*)w; w += (size_t)NK * 4;       // 10.8 MB
    u32* multibk  = (u32*)w; w += (size_t)nkw * 4;      // 0.34 MB
    int* bsums    = (int*)w;

    hipMemsetAsync(bits, 0, (size_t)NWp * 8, stream);
    hipMemsetAsync(minE, 0x7F, (size_t)NK * 4, stream);
    hipMemsetAsync(multibk, 0, (size_t)nkw * 4, stream);

    int nb9 = (N * 9 + 255) / 256;
    k_mark<<<nb9, 256, 0, stream>>>(si, N, bits);
    s1_tilesum<<<NT, 256, 0, stream>>>(bits, tsums);
    k_scanB<<<1, 1024, 0, stream>>>(tsums, NT);
    s3_wprefix<<<NT, 256, 0, stream>>>(bits, tsums, wprefix);
    k_kid<<<nb9, 256, 0, stream>>>(si, N, bits, wprefix, kid, minE);
    k_flagsum<<<NB, 256, 0, stream>>>(kid, minE, NK, multibk, bsums);
    k_scanB<<<1, 1024, 0, stream>>>(bsums, NB);
    k_scanC<<<NB, 256, 0, stream>>>(kid, minE, bsums, si, N, NK, out_key, rank_key);
    k_zmt<<<512, 256, 0, stream>>>(multibk, rank_key, bsums, NB, NK, nkw,
                                   out_key, (float4*)outF);
    k_final<<<(NK * 8 + 255) / 256, 256, 0, stream>>>(kid, rank_key, multibk,
                                                      feat4, km, outF, NK);
}